// Round 3
// baseline (209.040 us; speedup 1.0000x reference)
//
#include <hip/hip_runtime.h>
#include <math.h>

// Problem constants (fixed by reference)
#define GRIDN   14
#define BOXN    2
#define LABELN  20
#define ALL_BOX 10          // 5*BOXN
#define CCH     30          // ALL_BOX + LABELN channels per cell
#define TILE_CELLS  64      // per-WAVE tile (one cell per lane)
#define TILE_FLOATS (TILE_CELLS * CCH)   // 1920 floats = 7680 B per tensor
#define WAVES_PER_BLOCK 4
#define PERSISTENT_BLOCKS 512            // 2 blocks/CU resident, persistent

__global__ void yolo_zero_kernel(float* out, int n) {
    int i = blockIdx.x * blockDim.x + threadIdx.x;
    if (i < n) out[i] = 0.0f;
}

// Async global->LDS DMA. LDS dst is wave-uniform base; HW scatters lane*size.
__device__ __forceinline__ void async_load16(const float* g, float* l) {
    __builtin_amdgcn_global_load_lds(
        (const __attribute__((address_space(1))) void*)g,
        (__attribute__((address_space(3))) void*)l, 16, 0, 0);
}
__device__ __forceinline__ void async_load4(const float* g, float* l) {
    __builtin_amdgcn_global_load_lds(
        (const __attribute__((address_space(1))) void*)g,
        (__attribute__((address_space(3))) void*)l, 4, 0, 0);
}

// s_waitcnt immediates (gfx9 encoding: vm[3:0]|[15:14], exp[6:4], lgkm[11:8])
#define WAITCNT_VM0_ONLY   0x0F70   // vmcnt(0), lgkm/exp = no-wait
#define WAITCNT_LGKM0_ONLY 0xC07F   // lgkmcnt(0), vm/exp = no-wait

__global__ __launch_bounds__(256) void yolo_loss_kernel(
    const float* __restrict__ preds,
    const float* __restrict__ truths,
    float* __restrict__ out,
    int ntiles)
{
#pragma clang fp contract(off)
    // Per-wave private slices: 4 waves * (1920 P + 1920 T) * 4B = 61440 B -> 2 blocks/CU
    __shared__ float sbuf[WAVES_PER_BLOCK * 2 * TILE_FLOATS];

    const int tid  = threadIdx.x;
    const int wave = tid >> 6;
    const int lane = tid & 63;

    float* sP = sbuf + wave * (2 * TILE_FLOATS);
    float* sT = sP + TILE_FLOATS;

    const int gwave = blockIdx.x * WAVES_PER_BLOCK + wave;
    const int nw    = gridDim.x * WAVES_PER_BLOCK;   // 2048 wave-pipelines

    const float CELL = (float)(1.0 / (double)GRIDN);
    float acc = 0.0f;

    // NO __syncthreads anywhere: each wave pipelines independently (8/CU),
    // waiting only on its own vmcnt — avoids block-lockstep memory/compute phasing.
    for (int tile = gwave; tile < ntiles; tile += nw) {
        const float* gp = preds  + (long long)tile * TILE_FLOATS;
        const float* gt = truths + (long long)tile * TILE_FLOATS;

        // 7680 B per tensor = 7 x (64 lanes x 16B) + 2 x (64 lanes x 4B)
#pragma unroll
        for (int c = 0; c < 7; ++c) {
            async_load16(gp + c * 256 + lane * 4, sP + c * 256);
            async_load16(gt + c * 256 + lane * 4, sT + c * 256);
        }
#pragma unroll
        for (int c = 0; c < 2; ++c) {
            async_load4(gp + 1792 + c * 64 + lane, sP + 1792 + c * 64);
            async_load4(gt + 1792 + c * 64 + lane, sT + 1792 + c * 64);
        }
        __builtin_amdgcn_s_waitcnt(WAITCNT_VM0_ONLY);  // per-wave DMA drain only

        const float* p = sP + lane * CCH;
        const float* t = sT + lane * CCH;

        const float tx = t[0], ty = t[1], tw = t[2], th_ = t[3], tconf = t[4];
        const bool obj = tconf > 0.0f;

        // Truth box (scaled center, half-extent) — same op order as reference
        const float tcx = CELL * tx, tcy = CELL * ty;
        const float thx = tw * 0.5f, thy = th_ * 0.5f;
        const float tltx = tcx - thx, tlty = tcy - thy;
        const float trbx = tcx + thx, trby = tcy + thy;
        const float ta = (trbx - tltx) * (trby - tlty);

        float iou[BOXN], conf[BOXN];
        float pr[BOXN][5];
#pragma unroll
        for (int b = 0; b < BOXN; ++b) {
            const float bx = p[b * 5 + 0], by = p[b * 5 + 1];
            const float bw = p[b * 5 + 2], bh = p[b * 5 + 3];
            const float bc = p[b * 5 + 4];
            pr[b][0] = bx; pr[b][1] = by; pr[b][2] = bw; pr[b][3] = bh; pr[b][4] = bc;
            conf[b] = bc;
            const float pcx = CELL * bx, pcy = CELL * by;
            const float phx = bw * 0.5f, phy = bh * 0.5f;
            const float pltx = pcx - phx, plty = pcy - phy;
            const float prbx = pcx + phx, prby = pcy + phy;
            const float ltx = fmaxf(pltx, tltx), lty = fmaxf(plty, tlty);
            const float rbx = fminf(prbx, trbx), rby = fminf(prby, trby);
            const float whx = fmaxf(rbx - ltx, 0.0f);
            const float why = fmaxf(rby - lty, 0.0f);
            const float inter = whx * why;
            const float pa = (prbx - pltx) * (prby - plty);
            iou[b] = inter / (pa + ta - inter);
        }

        const float max_iou = fmaxf(iou[0], iou[1]);
        // jnp argmax first-occurrence + tie rule (n_tied>1 -> conf argmax)
        int resp;
        if (iou[0] == iou[1]) resp = (conf[0] >= conf[1]) ? 0 : 1;
        else                  resp = (iou[0] > iou[1]) ? 0 : 1;

        const float* prr = pr[resp];

        const float dcx = prr[0] - tx;
        const float dcy = prr[1] - ty;
        const float center = dcx * dcx + dcy * dcy;

        const float dsx = sqrtf(prr[2]) - sqrtf(tw);
        const float dsy = sqrtf(prr[3]) - sqrtf(th_);
        const float size = dsx * dsx + dsy * dsy;

        const float dconf = prr[4] - max_iou;
        const float conf_resp = dconf * dconf;

        const float c_other = conf[1 - resp];
        const float conf_noresp = c_other * c_other;

        const float conf_noobj = conf[0] * conf[0] + conf[1] * conf[1];

        float label = 0.0f;
#pragma unroll
        for (int k = ALL_BOX; k < CCH; ++k) {
            const float d = p[k] - t[k];
            label += d * d;
        }

        const float w  = obj ? 1.0f : 0.0f;
        const float nw2 = obj ? 0.0f : 1.0f;
        acc += w * (5.0f * (center + size) + conf_resp + 0.5f * conf_noresp + label)
             + nw2 * (0.5f * conf_noobj);

        // WAR guard: all LDS reads retired before next tile's DMA overwrites slice
        __builtin_amdgcn_s_waitcnt(WAITCNT_LGKM0_ONLY);
    }

    // Per-wave reduction -> one atomic per wave (2048 total, no barrier needed)
#pragma unroll
    for (int off = 32; off > 0; off >>= 1) acc += __shfl_down(acc, off, 64);
    if (lane == 0) atomicAdd(out, acc * (1.0f / 4096.0f));
}

extern "C" void kernel_launch(void* const* d_in, const int* in_sizes, int n_in,
                              void* d_out, int out_size, void* d_ws, size_t ws_size,
                              hipStream_t stream) {
    const float* preds  = (const float*)d_in[0];
    const float* truths = (const float*)d_in[1];
    float* out = (float*)d_out;

    const int ncells = in_sizes[0] / CCH;        // 4096*14*14 = 802816
    const int ntiles = ncells / TILE_CELLS;      // 12544 (exact)

    // d_out is re-poisoned before every timed launch -> zero it on-stream first.
    yolo_zero_kernel<<<(out_size + 255) / 256, 256, 0, stream>>>(out, out_size);
    yolo_loss_kernel<<<PERSISTENT_BLOCKS, 256, 0, stream>>>(preds, truths, out, ntiles);
}